// Round 4
// baseline (254.464 us; speedup 1.0000x reference)
//
#include <hip/hip_runtime.h>

// NetAndTexture: fused feature-gather + barycentric blend + SH2 eval.
// LDS-staged gathers: Phase A = row indices/weights, Phase B = line-coherent
// row copy into LDS (consecutive lanes read consecutive 16B chunks of the
// same feature row), Phase C = round-3 compute (8 lanes/pixel) from LDS.
// out layout (floats): [HW*16 fg feats][HW*16 bg feats][HW fg mask][HW bg mask]

constexpr float SH_C0 = 0.28209479177387814f;
constexpr float SH_C1 = 0.4886025119029199f;
constexpr float C20 =  1.0925484305920792f;
constexpr float C21 = -1.0925484305920792f;
constexpr float C22 =  0.31539156525252005f;
constexpr float C23 = -1.0925484305920792f;
constexpr float C24 =  0.5462742152960396f;
constexpr float INV_R2 = 1.0f / (0.006f * 0.006f);

constexpr int PPB     = 16;        // pixels per block
constexpr int THREADS = 128;       // 2 waves
constexpr int NROWS   = PPB * 4;   // 64 row slots (pixel x {frag1,v0,v1,v2})
constexpr int ROW_DW  = 76;        // 72 floats + 4 pad (16B-aligned stride)

__global__ __launch_bounds__(THREADS) void net_tex_stage(
    const float* __restrict__ features,
    const float* __restrict__ dists,
    const float* __restrict__ bary,
    const float* __restrict__ rd,
    const int*  __restrict__ faces,
    const int*  __restrict__ f1idx,
    const int*  __restrict__ p2f,
    float* __restrict__ out,
    int HW, int N)
{
    __shared__ float s_rows[NROWS * ROW_DW];
    __shared__ int   s_idx[NROWS];
    __shared__ float s_w[NROWS];

    const int tid = threadIdx.x;
    const int P0  = blockIdx.x * PPB;

    // ---- Phase A: row indices + weights (one thread per (pixel,role) slot)
    if (tid < NROWS) {
        int pix  = tid >> 2;
        int role = tid & 3;
        int p    = P0 + pix;
        int idx  = -1;
        float w  = 0.0f;
        if (p < N) {
            if (role == 0) {
                int i1 = f1idx[p];
                if (i1 >= 0) { idx = i1; w = 1.0f - dists[p] * INV_R2; }
            } else {
                int f2 = p2f[p];
                if (f2 >= 0) {
                    idx = faces[3 * f2 + (role - 1)];
                    w   = bary[(size_t)3 * p + (role - 1)];
                }
            }
        }
        s_idx[tid] = idx;
        s_w[tid]   = w;
    }
    __syncthreads();

    // ---- Phase B: stage rows into LDS, line-coherent global reads.
    // t enumerates (row, chunk); consecutive lanes -> consecutive chunks of
    // the same row -> each load instr touches ~4 rows x ~5 lines.
    for (int t = tid; t < NROWS * 18; t += THREADS) {
        int rid = t / 18;
        int m   = t - rid * 18;
        int idx = s_idx[rid];
        float4 v = make_float4(0.0f, 0.0f, 0.0f, 0.0f);
        if (idx >= 0)
            v = ((const float4*)(features + (size_t)idx * 72))[m];
        *(float4*)(s_rows + rid * ROW_DW + m * 4) = v;
    }
    __syncthreads();

    // ---- Phase C: compute, 8 lanes per pixel (role = r>>1, half = r&1).
    int pix  = tid >> 3;
    int r    = tid & 7;
    int role = r >> 1;
    int half = r & 1;
    int p    = P0 + pix;
    if (p >= N) return;

    int s  = (p >= HW) ? 1 : 0;
    int hw = p - s * HW;

    // dirs = flip(ray_dirs over H,W) -> rd[k*HW + (HW-1-hw)]
    float x = rd[HW   - 1 - hw];
    float y = rd[2*HW - 1 - hw];
    float z = rd[3*HW - 1 - hw];
    float xx = x*x, yy = y*y, zz = z*z;
    float c[9];
    c[0] = SH_C0;
    c[1] = -SH_C1 * y;
    c[2] =  SH_C1 * z;
    c[3] = -SH_C1 * x;
    c[4] = C20 * x * y;
    c[5] = C21 * y * z;
    c[6] = C22 * (2.0f*zz - xx - yy);
    c[7] = C23 * x * z;
    c[8] = C24 * (xx - yy);

    int   slot  = pix * 4 + role;
    bool  valid = s_idx[slot] >= 0;
    float w     = s_w[slot];

    const float4* row = (const float4*)(s_rows + slot * ROW_DW) + half * 9;

    float d[4];
    #pragma unroll
    for (int j = 0; j < 4; j++) d[j] = 0.0f;

    #pragma unroll
    for (int ch = 0; ch < 9; ch++) {
        float4 v = row[ch];
        const int e = ch * 4;            // 36%9==0: same pattern both halves
        d[(e+0)/9] += c[(e+0)%9] * v.x;
        d[(e+1)/9] += c[(e+1)%9] * v.y;
        d[(e+2)/9] += c[(e+2)%9] * v.z;
        d[(e+3)/9] += c[(e+3)%9] * v.w;
    }
    #pragma unroll
    for (int j = 0; j < 4; j++) d[j] *= w;   // w==0 for invalid rows

    // Sum roles 1-3 (bg) within the 8-lane group; role0 contribution zeroed.
    float sum[4];
    #pragma unroll
    for (int j = 0; j < 4; j++) {
        float t = (role == 0) ? 0.0f : d[j];
        t += __shfl_xor(t, 2, 64);
        t += __shfl_xor(t, 4, 64);
        sum[j] = t;
    }

    // final mask = m1 || m2 over the 8-lane group.
    unsigned long long bal = __ballot(valid);
    int lane = tid & 63;
    bool any = ((bal >> (lane & ~7)) & 0xFFULL) != 0;

    float4* o = (float4*)(out + (size_t)p * 16);
    if (r == 0) {
        o[0] = make_float4(d[0], d[1], d[2], d[3]);         // fg ch 0-3
    } else if (r == 1) {
        o[1] = make_float4(d[0], d[1], d[2], d[3]);         // fg ch 4-7
    } else if (r == 2) {
        o[2] = make_float4(sum[0], sum[1], sum[2], sum[3]); // bg ch 8-11
    } else if (r == 3) {
        o[3] = make_float4(sum[0], sum[1], sum[2], sum[3]); // bg ch 12-15
    } else if (r == 4) {
        out[(size_t)2 * HW * 16 + p] = any ? 1.0f : 0.0f;
    }
}

extern "C" void kernel_launch(void* const* d_in, const int* in_sizes, int n_in,
                              void* d_out, int out_size, void* d_ws, size_t ws_size,
                              hipStream_t stream)
{
    const float* features = (const float*)d_in[0];
    const float* dists    = (const float*)d_in[1];
    const float* bary     = (const float*)d_in[2];
    const float* rd       = (const float*)d_in[3];
    const int*   faces    = (const int*)d_in[4];
    const int*   f1idx    = (const int*)d_in[5];
    const int*   p2f      = (const int*)d_in[6];
    float* out = (float*)d_out;

    int HW = in_sizes[1] / 2;   // frag1_dists has 2*H*W elements
    int N  = 2 * HW;            // pixel-layers

    int grid = (N + PPB - 1) / PPB;
    hipLaunchKernelGGL(net_tex_stage, dim3(grid), dim3(THREADS), 0, stream,
                       features, dists, bary, rd, faces, f1idx, p2f, out, HW, N);
}

// Round 5
// 207.359 us; speedup vs baseline: 1.2272x; 1.2272x over previous
//
#include <hip/hip_runtime.h>

// NetAndTexture: fused feature-gather + barycentric blend + SH2 eval.
// 8 lanes per pixel-layer: r = role*2 + half.
//   role 0   = frag1 row (weight 1-d/R^2) -> out ch 0-7
//   role 1-3 = triangle vertex rows (x bary) -> out ch 8-15
// Pair-coherent gathers: lane (role,half) reads chunks 2*ch+half, so the
// two lanes of a role-pair touch adjacent 16B chunks (same 32B segment) in
// every load instruction -> 32 distinct lines/instr instead of 64.
// Loads stay converged (buffered in v[9]); only the accumulation arithmetic
// diverges on `half` to keep all register indices compile-time constant.
// out layout (floats): [HW*16 fg feats][HW*16 bg feats][HW fg mask][HW bg mask]

constexpr float SH_C0 = 0.28209479177387814f;
constexpr float SH_C1 = 0.4886025119029199f;
constexpr float C20 =  1.0925484305920792f;
constexpr float C21 = -1.0925484305920792f;
constexpr float C22 =  0.31539156525252005f;
constexpr float C23 = -1.0925484305920792f;
constexpr float C24 =  0.5462742152960396f;
constexpr float INV_R2 = 1.0f / (0.006f * 0.006f);

template<int HALF>
__device__ __forceinline__ void accum8(const float4 v[9], const float c[9],
                                       float d[8])
{
    #pragma unroll
    for (int ch = 0; ch < 9; ch++) {
        const int e = (2 * ch + HALF) * 4;   // element index within 72-row
        d[(e+0)/9] += c[(e+0)%9] * v[ch].x;
        d[(e+1)/9] += c[(e+1)%9] * v[ch].y;
        d[(e+2)/9] += c[(e+2)%9] * v[ch].z;
        d[(e+3)/9] += c[(e+3)%9] * v[ch].w;
    }
}

__global__ __launch_bounds__(256) void net_tex_pair(
    const float* __restrict__ features,
    const float* __restrict__ dists,
    const float* __restrict__ bary,
    const float* __restrict__ rd,
    const int*  __restrict__ faces,
    const int*  __restrict__ f1idx,
    const int*  __restrict__ p2f,
    float* __restrict__ out,
    int HW, int N)
{
    int q = blockIdx.x * blockDim.x + threadIdx.x;
    int p = q >> 3;            // pixel-layer (uniform across 8-lane group)
    int r = q & 7;
    if (p >= N) return;
    int role = r >> 1;
    int half = r & 1;

    int s  = (p >= HW) ? 1 : 0;
    int hw = p - s * HW;

    // dirs = flip(ray_dirs over H,W) -> rd[k*HW + (HW-1-hw)]
    float x = rd[HW   - 1 - hw];
    float y = rd[2*HW - 1 - hw];
    float z = rd[3*HW - 1 - hw];
    float xx = x*x, yy = y*y, zz = z*z;
    float c[9];
    c[0] = SH_C0;
    c[1] = -SH_C1 * y;
    c[2] =  SH_C1 * z;
    c[3] = -SH_C1 * x;
    c[4] = C20 * x * y;
    c[5] = C21 * y * z;
    c[6] = C22 * (2.0f*zz - xx - yy);
    c[7] = C23 * x * z;
    c[8] = C24 * (xx - yy);

    // Pick this lane's feature row + weight (shared by the half-pair).
    int   idx;
    float w;
    bool  valid;
    if (role == 0) {
        int i1 = f1idx[p];
        valid = (i1 >= 0);
        idx = valid ? i1 : 0;
        w = 1.0f - dists[p] * INV_R2;
    } else {
        int f2 = p2f[p];
        valid = (f2 >= 0);
        int fb = (valid ? f2 : 0) * 3;
        idx = faces[fb + (role - 1)];
        w = bary[(size_t)p * 3 + (role - 1)];
    }

    float d[8];
    #pragma unroll
    for (int j = 0; j < 8; j++) d[j] = 0.0f;

    if (valid) {
        const float4* row =
            (const float4*)(features + (size_t)idx * 72) + half;
        float4 v[9];
        #pragma unroll
        for (int ch = 0; ch < 9; ch++)
            v[ch] = row[2 * ch];           // chunk 2*ch + half (pair-adjacent)
        if (half == 0) accum8<0>(v, c, d);
        else           accum8<1>(v, c, d);
        #pragma unroll
        for (int j = 0; j < 8; j++) d[j] *= w;
    }

    // Sum the half-pair: both lanes of a role-pair get the full row result.
    float rs[8];
    #pragma unroll
    for (int j = 0; j < 8; j++)
        rs[j] = d[j] + __shfl_xor(d[j], 1, 64);

    // bg = sum of roles 1-3 (role0 contribution zeroed).
    float bg[8];
    #pragma unroll
    for (int j = 0; j < 8; j++) {
        float t = (role == 0) ? 0.0f : rs[j];
        t += __shfl_xor(t, 2, 64);
        t += __shfl_xor(t, 4, 64);
        bg[j] = t;
    }

    // final mask = m1 || m2 over the 8-lane group.
    unsigned long long bal = __ballot(valid);
    int lane = threadIdx.x & 63;
    bool any = ((bal >> (lane & ~7)) & 0xFFULL) != 0;

    float4* o = (float4*)(out + (size_t)p * 16);
    if (r == 0) {
        o[0] = make_float4(rs[0], rs[1], rs[2], rs[3]);   // fg ch 0-3
    } else if (r == 1) {
        o[1] = make_float4(rs[4], rs[5], rs[6], rs[7]);   // fg ch 4-7
    } else if (r == 2) {
        o[2] = make_float4(bg[0], bg[1], bg[2], bg[3]);   // bg ch 8-11
    } else if (r == 3) {
        o[3] = make_float4(bg[4], bg[5], bg[6], bg[7]);   // bg ch 12-15
    } else if (r == 4) {
        out[(size_t)2 * HW * 16 + p] = any ? 1.0f : 0.0f;
    }
}

extern "C" void kernel_launch(void* const* d_in, const int* in_sizes, int n_in,
                              void* d_out, int out_size, void* d_ws, size_t ws_size,
                              hipStream_t stream)
{
    const float* features = (const float*)d_in[0];
    const float* dists    = (const float*)d_in[1];
    const float* bary     = (const float*)d_in[2];
    const float* rd       = (const float*)d_in[3];
    const int*   faces    = (const int*)d_in[4];
    const int*   f1idx    = (const int*)d_in[5];
    const int*   p2f      = (const int*)d_in[6];
    float* out = (float*)d_out;

    int HW = in_sizes[1] / 2;   // frag1_dists has 2*H*W elements
    int N  = 2 * HW;            // pixel-layers
    long long threads = (long long)N * 8;

    const int block = 256;
    const int grid  = (int)((threads + block - 1) / block);
    hipLaunchKernelGGL(net_tex_pair, dim3(grid), dim3(block), 0, stream,
                       features, dists, bary, rd, faces, f1idx, p2f, out, HW, N);
}